// Round 1
// baseline (312.696 us; speedup 1.0000x reference)
//
#include <hip/hip_runtime.h>
#include <math.h>

#define NB   16     // batch
#define IMG  128    // input image side
#define CNV  300    // canvas side after pad_fov + diag_pad (42+44 = 86 offset)
#define NANG 300
#define NDET 300
#define RE   4      // emission blur radius
#define RA   8      // attenuation blur radius
#define WE   (IMG + 2*RE)   // 136
#define WA   (IMG + 2*RA)   // 144

// Gaussian taps: sigma_img = 1/sqrt(ln2) -> tap = 2^(-d^2/2); sigma_att = 2/sqrt(ln2) -> 2^(-d^2/8)
// Normalized in double at compile time (matches numpy f64 normalize -> f32 cast).
__device__ __constant__ float KE[9] = {
  (float)(0.00390625            / 3.0104144100214136),
  (float)(0.04419417382415922   / 3.0104144100214136),
  (float)(0.25                  / 3.0104144100214136),
  (float)(0.7071067811865476    / 3.0104144100214136),
  (float)(1.0                   / 3.0104144100214136),
  (float)(0.7071067811865476    / 3.0104144100214136),
  (float)(0.25                  / 3.0104144100214136),
  (float)(0.04419417382415922   / 3.0104144100214136),
  (float)(0.00390625            / 3.0104144100214136)
};
__device__ __constant__ float KA[17] = {
  (float)(0.00390625            / 6.019333926786741),
  (float)(0.014328188175072987  / 6.019333926786741),
  (float)(0.04419417382415922   / 6.019333926786741),
  (float)(0.11462550540058389   / 6.019333926786741),
  (float)(0.25                  / 6.019333926786741),
  (float)(0.4585020216023356    / 6.019333926786741),
  (float)(0.7071067811865476    / 6.019333926786741),
  (float)(0.9170040432046712    / 6.019333926786741),
  (float)(1.0                   / 6.019333926786741),
  (float)(0.9170040432046712    / 6.019333926786741),
  (float)(0.7071067811865476    / 6.019333926786741),
  (float)(0.4585020216023356    / 6.019333926786741),
  (float)(0.25                  / 6.019333926786741),
  (float)(0.11462550540058389   / 6.019333926786741),
  (float)(0.04419417382415922   / 6.019333926786741),
  (float)(0.014328188175072987  / 6.019333926786741),
  (float)(0.00390625            / 6.019333926786741)
};

// K1: horizontal blur of the raw 128x128 images into hE[b][y][xi] (xi: canvas x-82)
// and hA[b][y][xi] (xi: canvas x-78). Zero-extension == reference reflect (margin is zeros).
__global__ void k_hblur(const float* __restrict__ img, const float* __restrict__ att,
                        float* __restrict__ hE, float* __restrict__ hA) {
  int id = blockIdx.x * 256 + threadIdx.x;
  if (blockIdx.y == 0) {
    if (id >= NB * IMG * WE) return;
    int xi = id % WE; int rest = id / WE; int y = rest % IMG; int b = rest / IMG;
    const float* src = img + (b * IMG + y) * IMG;
    float acc = 0.f;
#pragma unroll
    for (int d = 0; d < 9; ++d) {
      int col = xi - 2 * RE + d;
      if (col >= 0 && col < IMG) acc = fmaf(KE[d], src[col], acc);
    }
    hE[id] = acc;
  } else {
    if (id >= NB * IMG * WA) return;
    int xi = id % WA; int rest = id / WA; int y = rest % IMG; int b = rest / IMG;
    const float* src = att + (b * IMG + y) * IMG;
    float acc = 0.f;
#pragma unroll
    for (int d = 0; d < 17; ++d) {
      int col = xi - 2 * RA + d;
      if (col >= 0 && col < IMG) acc = fmaf(KA[d], src[col], acc);
    }
    hA[id] = acc;
  }
}

// K2: vertical blur -> 300x300 canvas, layout [y][x][b] float2{E, 0.01*A}. Zero outside boxes.
__global__ void k_canvas(const float* __restrict__ hE, const float* __restrict__ hA,
                         float2* __restrict__ EA) {
  int id = blockIdx.x * 256 + threadIdx.x;   // 300*300*16 = 1,440,000 exactly = 5625*256
  int b = id & 15; int pix = id >> 4; int x = pix % CNV; int y = pix / CNV;
  float e = 0.f, a = 0.f;
  if (x >= 82 && x < 218 && y >= 82 && y < 218) {
    const float* h = hE + (b * IMG) * WE + (x - 82);
    float acc = 0.f;
#pragma unroll
    for (int d = 0; d < 9; ++d) {
      int row = y - 90 + d;
      if (row >= 0 && row < IMG) acc = fmaf(KE[d], h[row * WE], acc);
    }
    e = acc;
  }
  if (x >= 78 && x < 222 && y >= 78 && y < 222) {
    const float* h = hA + (b * IMG) * WA + (x - 78);
    float acc = 0.f;
#pragma unroll
    for (int d = 0; d < 17; ++d) {
      int row = y - 94 + d;
      if (row >= 0 && row < IMG) acc = fmaf(KA[d], h[row * WA], acc);
    }
    a = 0.01f * acc;   // ATT_SCALE folded in
  }
  EA[id] = make_float2(e, a);
}

// K3: radon over both images simultaneously + attenuation combine.
// Lane map: b = tid&15 (innermost -> coalesced pixel lines), 4 bins/wave, 16 bins/block.
// S layout: [a][j][b] (coalesced writes).
__global__ void k_radon(const float2* __restrict__ EA, float* __restrict__ S) {
  int t = threadIdx.x;
  int b  = t & 15;
  int jj = t >> 4;
  int j  = blockIdx.x * 16 + jj;
  int a  = blockIdx.y;
  if (j >= NDET) return;
  float th = (float)a * (float)(3.14159265358979323846 / 299.0);
  float c = cosf(th), s = sinf(th);
  float xj = fmaf((float)j, (float)(2.0 / 299.0), -1.0f);
  // px(i) = pb + s*i ; py(i) = qb + c*i   (sample step is exactly 1 px: 2/299*149.5 = 1)
  float pb = fmaf(c,  xj, 1.0f) * 149.5f - 149.5f * s;
  float qb = fmaf(-s, xj, 1.0f) * 149.5f - 149.5f * c;
  // support box (attenuation is the wider one: rows/cols 78..221 nonzero):
  // samples with px or py outside [77,222) contribute exactly 0. Use 0.5px safety margin.
  const float L = 76.5f, H = 222.5f;
  float lo = 0.f, hi = 299.0f;
  if (fabsf(s) > 1e-6f) {
    float inv = 1.0f / s;
    float t0 = (L - pb) * inv, t1 = (H - pb) * inv;
    lo = fmaxf(lo, fminf(t0, t1)); hi = fminf(hi, fmaxf(t0, t1));
  } else if (pb < L || pb > H) { hi = -1.f; }
  if (fabsf(c) > 1e-6f) {
    float inv = 1.0f / c;
    float t0 = (L - qb) * inv, t1 = (H - qb) * inv;
    lo = fmaxf(lo, fminf(t0, t1)); hi = fminf(hi, fmaxf(t0, t1));
  } else if (qb < L || qb > H) { hi = -1.f; }
  int i0 = (int)ceilf(lo);
  int i1 = (int)floorf(hi);
  float sumE = 0.f, sumA = 0.f;
  float fi = (float)i0;
  const float2* baseb = EA + b;
  for (int i = i0; i <= i1; ++i, fi += 1.0f) {
    float px = fmaf(fi, s, pb);
    float py = fmaf(fi, c, qb);
    float x0f = floorf(px), y0f = floorf(py);
    float wx = px - x0f,    wy = py - y0f;
    int x0 = (int)x0f, y0 = (int)y0f;
    const float2* p = baseb + (y0 * CNV + x0) * NB;
    float2 v00 = p[0];
    float2 v01 = p[NB];
    float2 v10 = p[CNV * NB];
    float2 v11 = p[CNV * NB + NB];
    float tE = fmaf(wx, v01.x - v00.x, v00.x);
    float bE = fmaf(wx, v11.x - v10.x, v10.x);
    sumE += fmaf(wy, bE - tE, tE);
    float tA = fmaf(wx, v01.y - v00.y, v00.y);
    float bA = fmaf(wx, v11.y - v10.y, v10.y);
    sumA += fmaf(wy, bA - tA, tA);
  }
  S[(a * NDET + j) * NB + b] = sumE * expf(-2.0f * sumA);  // VOXEL_MM = 2
}

// K4: per-angle 5-tap detector blur (reflect) + scale, write final [b][a][j].
__global__ void k_dblur(const float* __restrict__ S, const float* __restrict__ scale,
                        float* __restrict__ out) {
  int t = threadIdx.x;
  int b  = t & 15;
  int jj = t >> 4;
  int j  = blockIdx.x * 16 + jj;
  int a  = blockIdx.y;
  if (j >= NDET) return;
  float th = (float)a * (float)(3.14159265358979323846 / 299.0);
  float c = cosf(th), s = sinf(th);
  float u = fabsf(c) + fabsf(s);          // bw = 2u, sig = sigma_img/bw
  float u2 = u * u;
  float e1 = exp2f(-2.0f * u2);           // tap 1: 2^(-0.5*1*bw^2)
  float e2 = exp2f(-8.0f * u2);           // tap 2: 2^(-0.5*4*bw^2)
  float norm = 1.0f / (1.0f + 2.0f * (e1 + e2));
  float w2c = norm, w1c = e1 * norm, w0c = e2 * norm;
  const float* row = S + a * NDET * NB + b;
  float acc = 0.f;
#pragma unroll
  for (int tt = -2; tt <= 2; ++tt) {
    int jr = j + tt;
    if (jr < 0) jr = -jr;
    if (jr > 299) jr = 598 - jr;
    float w = (tt == 0) ? w2c : ((tt == 1 || tt == -1) ? w1c : w0c);
    acc = fmaf(w, row[jr * NB], acc);
  }
  out[(b * NANG + a) * NDET + j] = acc * scale[b];
}

extern "C" void kernel_launch(void* const* d_in, const int* in_sizes, int n_in,
                              void* d_out, int out_size, void* d_ws, size_t ws_size,
                              hipStream_t stream) {
  const float* img   = (const float*)d_in[0];
  const float* att   = (const float*)d_in[1];
  const float* scale = (const float*)d_in[2];
  float* out = (float*)d_out;
  float* ws  = (float*)d_ws;

  // ws layout (floats):
  //   [0 .. 573,440)        hE (278,528) + hA (294,912)   -- dead after K2
  //   [0 .. 1,440,000)      S  (written by K3, after hE/hA consumed; overlap OK, stream-ordered)
  //   [1,440,000 .. 4,320,000)  EA canvas (1.44M float2)
  // total 17.28 MB
  float*  hE = ws;
  float*  hA = ws + (NB * IMG * WE);             // 278,528
  float*  S  = ws;                                // reuses hE/hA region (+ more)
  float2* EA = (float2*)(ws + 1440000);

  k_hblur <<<dim3(1152, 2), 256, 0, stream>>>(img, att, hE, hA);
  k_canvas<<<dim3(5625),    256, 0, stream>>>(hE, hA, EA);
  k_radon <<<dim3(19, 300), 256, 0, stream>>>(EA, S);
  k_dblur <<<dim3(19, 300), 256, 0, stream>>>(S, scale, out);
}

// Round 2
// 215.807 us; speedup vs baseline: 1.4490x; 1.4490x over previous
//
#include <hip/hip_runtime.h>
#include <math.h>

#define NB   16     // batch
#define IMG  128    // input image side
#define CNV  300    // canvas side (pad_fov 42 + diag_pad 44 => image block at [86,214))
#define NANG 300
#define NDET 300
#define RE   4      // emission blur radius  (sigma = 1/sqrt(ln2))
#define RA   8      // attenuation blur radius (sigma = 2/sqrt(ln2))
#define WE   (IMG + 2*RE)   // 136 ; hE col xi <-> canvas x = xi+82 ; E support x in [82,218)
#define WA   (IMG + 2*RA)   // 144 ; hA col xi <-> canvas x = xi+78 ; A support x in [78,222)
#define BX   76             // packed canvas box base (canvas coords)
#define WB   148            // packed canvas box width: x,y in [76,224)

// Gaussian taps: sigma_img -> 2^(-d^2/2); sigma_att -> 2^(-d^2/8). f64 normalize, f32 cast (matches numpy).
__device__ __constant__ float KE[9] = {
  (float)(0.00390625            / 3.0104144100214136),
  (float)(0.04419417382415922   / 3.0104144100214136),
  (float)(0.25                  / 3.0104144100214136),
  (float)(0.7071067811865476    / 3.0104144100214136),
  (float)(1.0                   / 3.0104144100214136),
  (float)(0.7071067811865476    / 3.0104144100214136),
  (float)(0.25                  / 3.0104144100214136),
  (float)(0.04419417382415922   / 3.0104144100214136),
  (float)(0.00390625            / 3.0104144100214136)
};
__device__ __constant__ float KA[17] = {
  (float)(0.00390625            / 6.019333926786741),
  (float)(0.014328188175072987  / 6.019333926786741),
  (float)(0.04419417382415922   / 6.019333926786741),
  (float)(0.11462550540058389   / 6.019333926786741),
  (float)(0.25                  / 6.019333926786741),
  (float)(0.4585020216023356    / 6.019333926786741),
  (float)(0.7071067811865476    / 6.019333926786741),
  (float)(0.9170040432046712    / 6.019333926786741),
  (float)(1.0                   / 6.019333926786741),
  (float)(0.9170040432046712    / 6.019333926786741),
  (float)(0.7071067811865476    / 6.019333926786741),
  (float)(0.4585020216023356    / 6.019333926786741),
  (float)(0.25                  / 6.019333926786741),
  (float)(0.11462550540058389   / 6.019333926786741),
  (float)(0.04419417382415922   / 6.019333926786741),
  (float)(0.014328188175072987  / 6.019333926786741),
  (float)(0.00390625            / 6.019333926786741)
};

// K1: horizontal blur. hE[y][xi][b], hA[y][xi][b] (b innermost).
// Reads image rows coalesced; one strided store per thread (cheap).
__global__ void k_hblur(const float* __restrict__ img, const float* __restrict__ att,
                        float* __restrict__ hE, float* __restrict__ hA) {
  int xi = threadIdx.x;
  int y  = blockIdx.x;
  int b  = blockIdx.y;
  if (blockIdx.z == 0) {
    if (xi >= WE) return;
    const float* src = img + (b * IMG + y) * IMG;
    float acc = 0.f;
#pragma unroll
    for (int d = 0; d < 9; ++d) {
      int col = xi - 2 * RE + d;
      if (col >= 0 && col < IMG) acc = fmaf(KE[d], src[col], acc);
    }
    hE[(y * WE + xi) * NB + b] = acc;
  } else {
    if (xi >= WA) return;
    const float* src = att + (b * IMG + y) * IMG;
    float acc = 0.f;
#pragma unroll
    for (int d = 0; d < 17; ++d) {
      int col = xi - 2 * RA + d;
      if (col >= 0 && col < IMG) acc = fmaf(KA[d], src[col], acc);
    }
    hA[(y * WA + xi) * NB + b] = acc;
  }
}

// K2: vertical blur -> packed canvas over the live box [76,224)^2:
// P[y'][x'][b] = float4( E(y,x), 0.01*A(y,x), E(y,x+1), 0.01*A(y,x+1) ), x=x'+76, y=y'+76.
// Fully coalesced reads (b innermost in hE/hA) and writes.
__global__ void k_canvas(const float* __restrict__ hE, const float* __restrict__ hA,
                         float4* __restrict__ P) {
  int t  = threadIdx.x;
  int b  = t & 15;
  int xs = t >> 4;                      // 16 x-slots per block
  int xp = blockIdx.x * 16 + xs;        // x' in [0,148)
  int yp = blockIdx.y;                  // y' in [0,148)
  if (xp >= WB) return;

  float E0 = 0.f, E1 = 0.f, A0 = 0.f, A1 = 0.f;
  // E: col index xiE = x-82 = xp-6 ; rows y-90+d = yp-14+d
  {
    int xiE = xp - 6;
    bool c0 = (xiE >= 0) & (xiE < WE);
    bool c1 = (xiE + 1 >= 0) & (xiE + 1 < WE);
#pragma unroll
    for (int d = 0; d < 9; ++d) {
      int row = yp - 14 + d;
      if (row >= 0 && row < IMG) {
        const float* base = hE + (row * WE) * NB + b;
        if (c0) E0 = fmaf(KE[d], base[xiE * NB], E0);
        if (c1) E1 = fmaf(KE[d], base[(xiE + 1) * NB], E1);
      }
    }
  }
  // A: col index xiA = x-78 = xp-2 ; rows y-94+d = yp-18+d
  {
    int xiA = xp - 2;
    bool c0 = (xiA >= 0) & (xiA < WA);
    bool c1 = (xiA + 1 >= 0) & (xiA + 1 < WA);
#pragma unroll
    for (int d = 0; d < 17; ++d) {
      int row = yp - 18 + d;
      if (row >= 0 && row < IMG) {
        const float* base = hA + (row * WA) * NB + b;
        if (c0) A0 = fmaf(KA[d], base[xiA * NB], A0);
        if (c1) A1 = fmaf(KA[d], base[(xiA + 1) * NB], A1);
      }
    }
  }
  P[(yp * WB + xp) * NB + b] = make_float4(E0, 0.01f * A0, E1, 0.01f * A1);
}

// K3: radon for E and A together. Lanes: b = tid&15 (coalesced 256-B row-pair loads),
// 4 detector bins per wave. 4x unrolled with 8 dwordx4 loads in flight.
// Out-of-range samples are made exact zeros by clamping coords into the zero margin.
__global__ void k_radon(const float4* __restrict__ P, float* __restrict__ S) {
  int t = threadIdx.x;
  int b  = t & 15;
  int jj = t >> 4;
  int j  = blockIdx.x * 16 + jj;
  int a  = blockIdx.y;
  if (j >= NDET) return;
  float th = (float)a * (float)(3.14159265358979323846 / 299.0);
  float c = cosf(th), s = sinf(th);
  float xj = fmaf((float)j, (float)(2.0 / 299.0), -1.0f);
  // px(i) = pb + s*i ; py(i) = qb + c*i  (unit sample step: 2/299*149.5 = 1)
  float pb = fmaf(c,  xj, 1.0f) * 149.5f - 149.5f * s;
  float qb = fmaf(-s, xj, 1.0f) * 149.5f - 149.5f * c;
  // i-interval where the sample footprint can touch nonzero canvas (0.5px margin)
  const float L = 76.5f, H = 222.5f;
  float lo = 0.f, hi = 299.0f;
  if (fabsf(s) > 1e-6f) {
    float inv = 1.0f / s;
    float t0 = (L - pb) * inv, t1 = (H - pb) * inv;
    lo = fmaxf(lo, fminf(t0, t1)); hi = fminf(hi, fmaxf(t0, t1));
  } else if (pb < L || pb > H) { hi = -1.f; }
  if (fabsf(c) > 1e-6f) {
    float inv = 1.0f / c;
    float t0 = (L - qb) * inv, t1 = (H - qb) * inv;
    lo = fmaxf(lo, fminf(t0, t1)); hi = fminf(hi, fmaxf(t0, t1));
  } else if (qb < L || qb > H) { hi = -1.f; }
  int i0 = (int)ceilf(lo);
  int i1 = (int)floorf(hi);

  float sumE = 0.f, sumA = 0.f;
  // element offset: ((y0-76)*148 + (x0-76))*16 + b = (y0*148+x0)*16 + b - (76*149)*16
  const float4* Pb = P + b - (76 * 149) * 16;

  for (int i = i0; i <= i1; i += 4) {
    float4 q0[4], q1[4];
    float wxr[4], wyr[4];
#pragma unroll
    for (int u = 0; u < 4; ++u) {
      float fi = (float)(i + u);
      float px = fmaf(fi, s, pb);
      float py = fmaf(fi, c, qb);
      // clamp into margin: clamped samples read all-zero canvas -> exact 0 contribution
      px = fminf(fmaxf(px, 76.6f), 222.4f);
      py = fminf(fmaxf(py, 76.6f), 222.4f);
      float xf = floorf(px), yf = floorf(py);
      wxr[u] = px - xf;
      wyr[u] = py - yf;
      int idx = (int)yf * WB + (int)xf;
      const float4* p = Pb + idx * NB;
      q0[u] = p[0];
      q1[u] = p[WB * NB];
    }
#pragma unroll
    for (int u = 0; u < 4; ++u) {
      float wx = wxr[u], wy = wyr[u];
      float4 r0 = q0[u], r1 = q1[u];
      float ex0 = fmaf(wx, r0.z - r0.x, r0.x);
      float ax0 = fmaf(wx, r0.w - r0.y, r0.y);
      float ex1 = fmaf(wx, r1.z - r1.x, r1.x);
      float ax1 = fmaf(wx, r1.w - r1.y, r1.y);
      sumE += fmaf(wy, ex1 - ex0, ex0);
      sumA += fmaf(wy, ax1 - ax0, ax0);
    }
  }
  S[(a * NDET + j) * NB + b] = sumE * expf(-2.0f * sumA);  // VOXEL_MM = 2
}

// K4: per-angle 5-tap detector blur (reflect) + scale, write final [b][a][j].
__global__ void k_dblur(const float* __restrict__ S, const float* __restrict__ scale,
                        float* __restrict__ out) {
  int t = threadIdx.x;
  int b  = t & 15;
  int jj = t >> 4;
  int j  = blockIdx.x * 16 + jj;
  int a  = blockIdx.y;
  if (j >= NDET) return;
  float th = (float)a * (float)(3.14159265358979323846 / 299.0);
  float c = cosf(th), s = sinf(th);
  float u = fabsf(c) + fabsf(s);          // bw = 2u
  float u2 = u * u;
  float e1 = exp2f(-2.0f * u2);
  float e2 = exp2f(-8.0f * u2);
  float norm = 1.0f / (1.0f + 2.0f * (e1 + e2));
  float w2c = norm, w1c = e1 * norm, w0c = e2 * norm;
  const float* row = S + a * NDET * NB + b;
  float acc = 0.f;
#pragma unroll
  for (int tt = -2; tt <= 2; ++tt) {
    int jr = j + tt;
    if (jr < 0) jr = -jr;
    if (jr > 299) jr = 598 - jr;
    float w = (tt == 0) ? w2c : ((tt == 1 || tt == -1) ? w1c : w0c);
    acc = fmaf(w, row[jr * NB], acc);
  }
  out[(b * NANG + a) * NDET + j] = acc * scale[b];
}

extern "C" void kernel_launch(void* const* d_in, const int* in_sizes, int n_in,
                              void* d_out, int out_size, void* d_ws, size_t ws_size,
                              hipStream_t stream) {
  const float* img   = (const float*)d_in[0];
  const float* att   = (const float*)d_in[1];
  const float* scale = (const float*)d_in[2];
  float* out = (float*)d_out;
  float* ws  = (float*)d_ws;

  // ws layout (floats):
  //   P  : [0 .. 1,401,856)            packed canvas, 148*148*16 float4 (5.61 MB)
  //   S  : [1,401,856 .. 2,841,856)    sinogram 300*300*16 (5.76 MB)
  //   hE : [2,841,856 .. 3,120,384)    128*136*16 (1.11 MB)
  //   hA : [3,120,384 .. 3,415,296)    128*144*16 (1.18 MB)
  // total 13.66 MB
  float4* P  = (float4*)ws;
  float*  S  = ws + 1401856;
  float*  hE = ws + 2841856;
  float*  hA = ws + 3120384;

  k_hblur <<<dim3(IMG, NB, 2), 192, 0, stream>>>(img, att, hE, hA);
  k_canvas<<<dim3(10, WB),     256, 0, stream>>>(hE, hA, P);
  k_radon <<<dim3(19, NANG),   256, 0, stream>>>(P, S);
  k_dblur <<<dim3(19, NANG),   256, 0, stream>>>(S, scale, out);
}